// Round 1
// baseline (92.836 us; speedup 1.0000x reference)
//
#include <hip/hip_runtime.h>

// CEDiceMetrics: argmax over C channels -> confusion matrix -> dice/tp/psum/tsum
// B=2, C=8, N=D*H*W=4718592 (derived at runtime from in_sizes/out_size).

__global__ void conf_hist_kernel(const float* __restrict__ inp,
                                 const int* __restrict__ tgt,
                                 unsigned int* __restrict__ conf,
                                 int B, int C, long long Nv, long long N) {
    // Shared histogram: B*C*C bins (<= 256 supported)
    __shared__ unsigned int sh[256];
    const int nb = B * C * C;
    for (int i = threadIdx.x; i < nb; i += blockDim.x) sh[i] = 0u;
    __syncthreads();

    const long long totalv = (long long)B * Nv;
    const long long stride = (long long)gridDim.x * blockDim.x;

    for (long long wi = (long long)blockIdx.x * blockDim.x + threadIdx.x;
         wi < totalv; wi += stride) {
        // batch decomposition (B is tiny; avoid 64-bit div)
        int b = 0;
        long long iv = wi;
        while (iv >= Nv) { iv -= Nv; ++b; }

        const float4* ip = (const float4*)(inp + (long long)b * C * N);
        float4 best = ip[iv];                 // channel 0
        int bx = 0, by = 0, bz = 0, bw = 0;
        #pragma unroll
        for (int c = 1; c < 8; ++c) {
            if (c >= C) break;
            float4 v = ip[(long long)c * Nv + iv];
            if (v.x > best.x) { best.x = v.x; bx = c; }
            if (v.y > best.y) { best.y = v.y; by = c; }
            if (v.z > best.z) { best.z = v.z; bz = c; }
            if (v.w > best.w) { best.w = v.w; bw = c; }
        }
        const int4 t = ((const int4*)(tgt + (long long)b * N))[iv];
        const int base = b * C * C;
        atomicAdd(&sh[base + t.x * C + bx], 1u);
        atomicAdd(&sh[base + t.y * C + by], 1u);
        atomicAdd(&sh[base + t.z * C + bz], 1u);
        atomicAdd(&sh[base + t.w * C + bw], 1u);
    }

    // scalar tail (N not divisible by 4) — block 0 only
    const long long tail0 = Nv * 4;
    const long long tailN = N - tail0;
    if (tailN > 0 && blockIdx.x == 0) {
        for (long long k = threadIdx.x; k < (long long)B * tailN; k += blockDim.x) {
            int b = (int)(k / tailN);
            long long e = tail0 + (k - (long long)b * tailN);
            const float* p = inp + (long long)b * C * N;
            float bv = p[e];
            int bc = 0;
            for (int c = 1; c < C; ++c) {
                float v = p[(long long)c * N + e];
                if (v > bv) { bv = v; bc = c; }
            }
            int t = tgt[(long long)b * N + e];
            atomicAdd(&sh[b * C * C + t * C + bc], 1u);
        }
    }

    __syncthreads();
    for (int i = threadIdx.x; i < nb; i += blockDim.x) {
        unsigned int v = sh[i];
        if (v) atomicAdd(&conf[i], v);
    }
}

__global__ void finalize_kernel(const unsigned int* __restrict__ conf,
                                float* __restrict__ out,
                                int B, int C, int ncls) {
    int tid = threadIdx.x;
    if (tid >= B * C) return;
    int b = tid / C;
    int k = tid % C;
    const unsigned int* cb = conf + b * C * C;

    float tp = (float)cb[k * C + k];
    float tsum = 0.0f, psum = 0.0f;
    for (int j = 0; j < C; ++j) {
        tsum += (float)cb[k * C + j];  // sum over pred for target class k
        psum += (float)cb[j * C + k];  // sum over target for pred class k
    }
    int off = C - ncls;   // 1 when background dropped, 0 otherwise
    if (k >= off) {
        int idx = b * ncls + (k - off);
        int s = B * ncls;
        float dice = 2.0f * tp / (psum + tsum + 1e-5f);
        out[idx]         = dice;
        out[s + idx]     = tp;
        out[2 * s + idx] = psum;
        out[3 * s + idx] = tsum;
    }
}

extern "C" void kernel_launch(void* const* d_in, const int* in_sizes, int n_in,
                              void* d_out, int out_size, void* d_ws, size_t ws_size,
                              hipStream_t stream) {
    const float* inp = (const float*)d_in[0];
    const int* tgt = (const int*)d_in[1];
    float* out = (float*)d_out;
    unsigned int* conf = (unsigned int*)d_ws;

    // Derive shapes: in_sizes[0] = B*C*N, in_sizes[1] = B*N, out_size = 4*B*ncls
    const int C = in_sizes[0] / in_sizes[1];
    int ncls, B;
    if (C > 1 && out_size % (4 * (C - 1)) == 0 &&
        in_sizes[1] % (out_size / (4 * (C - 1))) == 0) {
        ncls = C - 1;                       // background dropped
        B = out_size / (4 * (C - 1));
    } else {
        ncls = C;
        B = out_size / (4 * C);
    }
    const long long N = (long long)in_sizes[1] / B;
    const long long Nv = N / 4;             // float4 work items per batch

    hipMemsetAsync(conf, 0, (size_t)(B * C * C) * sizeof(unsigned int), stream);

    const int block = 256;
    long long totalv = (long long)B * Nv;
    int grid = (int)((totalv + block - 1) / block);
    if (grid > 2048) grid = 2048;           // 8 blocks/CU cap, grid-stride the rest
    if (grid < 1) grid = 1;

    conf_hist_kernel<<<grid, block, 0, stream>>>(inp, tgt, conf, B, C, Nv, N);
    finalize_kernel<<<1, 64, 0, stream>>>(conf, out, B, C, ncls);
}

// Round 2
// 71.310 us; speedup vs baseline: 1.3019x; 1.3019x over previous
//
#include <hip/hip_runtime.h>

typedef float f32x4 __attribute__((ext_vector_type(4)));
typedef int   i32x4 __attribute__((ext_vector_type(4)));

// CEDiceMetrics: argmax over C channels -> per-batch CxC confusion matrix
// -> dice/tp/psum/tsum.  B=2, C=8, N=D*H*W=4718592 at bench shape.
//
// Grid: (blocks_x, B). Each block owns one batch -> loop-invariant base
// pointers, C*C-bin LDS histogram, one global atomicAdd per nonzero bin.

template <int CT>   // CT>0: compile-time channel count; CT==0: runtime C
__global__ __launch_bounds__(256, 6)
void conf_hist_kernel(const float* __restrict__ inp,
                      const int* __restrict__ tgt,
                      unsigned int* __restrict__ conf,
                      int Crt, long long N) {
    const int C = (CT > 0) ? CT : Crt;
    __shared__ unsigned int sh[64];          // C*C <= 64 supported here
    const int cc = C * C;
    for (int i = threadIdx.x; i < cc; i += blockDim.x) sh[i] = 0u;
    __syncthreads();

    const int b = blockIdx.y;
    const long long Nv4 = N >> 2;            // float4 per channel
    const f32x4* __restrict__ ip = (const f32x4*)(inp + (long long)b * C * N);
    const i32x4* __restrict__ tq = (const i32x4*)(tgt + (long long)b * N);

    const long long stride = (long long)gridDim.x * blockDim.x;
    for (long long i = (long long)blockIdx.x * blockDim.x + threadIdx.x;
         i < Nv4; i += stride) {
        f32x4 best = __builtin_nontemporal_load(ip + i);
        int bx = 0, by = 0, bz = 0, bw = 0;
        #pragma unroll
        for (int c = 1; c < ((CT > 0) ? CT : 8); ++c) {
            if (CT == 0 && c >= C) break;
            f32x4 v = __builtin_nontemporal_load(ip + (long long)c * Nv4 + i);
            if (v.x > best.x) { best.x = v.x; bx = c; }
            if (v.y > best.y) { best.y = v.y; by = c; }
            if (v.z > best.z) { best.z = v.z; bz = c; }
            if (v.w > best.w) { best.w = v.w; bw = c; }
        }
        i32x4 t = __builtin_nontemporal_load(tq + i);
        atomicAdd(&sh[t.x * C + bx], 1u);
        atomicAdd(&sh[t.y * C + by], 1u);
        atomicAdd(&sh[t.z * C + bz], 1u);
        atomicAdd(&sh[t.w * C + bw], 1u);
    }

    // scalar tail (N % 4 != 0) — first block of each batch row only
    const long long tail0 = Nv4 << 2;
    if (tail0 < N && blockIdx.x == 0) {
        const float* p = (const float*)ip;
        for (long long e = tail0 + threadIdx.x; e < N; e += blockDim.x) {
            float bv = p[e];
            int bc = 0;
            for (int c = 1; c < C; ++c) {
                float v = p[(long long)c * N + e];
                if (v > bv) { bv = v; bc = c; }
            }
            int t = ((const int*)tq)[e];
            atomicAdd(&sh[t * C + bc], 1u);
        }
    }

    __syncthreads();
    unsigned int* cb = conf + b * cc;
    for (int i = threadIdx.x; i < cc; i += blockDim.x) {
        unsigned int v = sh[i];
        if (v) atomicAdd(&cb[i], v);
    }
}

__global__ void finalize_kernel(const unsigned int* __restrict__ conf,
                                float* __restrict__ out,
                                int B, int C, int ncls) {
    int tid = threadIdx.x;
    if (tid >= B * C) return;
    int b = tid / C;
    int k = tid % C;
    const unsigned int* cb = conf + b * C * C;

    float tp = (float)cb[k * C + k];
    float tsum = 0.0f, psum = 0.0f;
    for (int j = 0; j < C; ++j) {
        tsum += (float)cb[k * C + j];   // row k: target class k over preds
        psum += (float)cb[j * C + k];   // col k: pred class k over targets
    }
    int off = C - ncls;                 // 1 when background dropped
    if (k >= off) {
        int idx = b * ncls + (k - off);
        int s = B * ncls;
        float dice = 2.0f * tp / (psum + tsum + 1e-5f);
        out[idx]         = dice;
        out[s + idx]     = tp;
        out[2 * s + idx] = psum;
        out[3 * s + idx] = tsum;
    }
}

extern "C" void kernel_launch(void* const* d_in, const int* in_sizes, int n_in,
                              void* d_out, int out_size, void* d_ws, size_t ws_size,
                              hipStream_t stream) {
    const float* inp = (const float*)d_in[0];
    const int* tgt = (const int*)d_in[1];
    float* out = (float*)d_out;
    unsigned int* conf = (unsigned int*)d_ws;

    // in_sizes[0] = B*C*N, in_sizes[1] = B*N, out_size = 4*B*ncls
    const int C = in_sizes[0] / in_sizes[1];
    int ncls, B;
    if (C > 1 && out_size % (4 * (C - 1)) == 0 &&
        in_sizes[1] % (out_size / (4 * (C - 1))) == 0) {
        ncls = C - 1;                   // background dropped
        B = out_size / (4 * (C - 1));
    } else {
        ncls = C;
        B = out_size / (4 * C);
    }
    const long long N = (long long)in_sizes[1] / B;
    const long long Nv4 = N >> 2;

    hipMemsetAsync(conf, 0, (size_t)(B * C * C) * sizeof(unsigned int), stream);

    const int block = 256;
    // ~6 float4-iterations per thread; 4718592/4 = 768*256*6 exactly -> even split
    long long bx = (Nv4 + (long long)block * 6 - 1) / ((long long)block * 6);
    if (bx < 1) bx = 1;
    if (bx > 4096) bx = 4096;
    dim3 grid((unsigned)bx, (unsigned)B);

    if (C == 8)
        conf_hist_kernel<8><<<grid, block, 0, stream>>>(inp, tgt, conf, C, N);
    else
        conf_hist_kernel<0><<<grid, block, 0, stream>>>(inp, tgt, conf, C, N);

    finalize_kernel<<<1, 64, 0, stream>>>(conf, out, B, C, ncls);
}